// Round 10
// baseline (2108.198 us; speedup 1.0000x reference)
//
#include <hip/hip_runtime.h>
#include <cstddef>
#include <cstdint>

#define NA_C 200000
#define NF_C 50000
#define EA_C 800000
#define EF_C 200000
#define NG_C 4096
#define DD 128
#define HH 256
#define SC_CHUNK 2048
#define NPW 8        // nodes per wave in streaming aggregation kernels

typedef unsigned short u16;
typedef unsigned int   u32;
typedef float f32x4 __attribute__((ext_vector_type(4)));
typedef short s16x8 __attribute__((ext_vector_type(8)));

__device__ inline float bf2f(u16 h) { return __uint_as_float(((u32)h) << 16); }
__device__ inline u16 f2bf(float f) {
    u32 u = __float_as_uint(f);
    return (u16)((u + 0x7fffu + ((u >> 16) & 1u)) >> 16);
}
__device__ inline float2 up2(u32 u) {
    return make_float2(__uint_as_float(u << 16), __uint_as_float(u & 0xffff0000u));
}
__device__ inline u32 pk2(float x, float y) { return (u32)f2bf(x) | ((u32)f2bf(y) << 16); }

// async global->LDS, 16B per lane; LDS dest = wave-uniform base + lane*16
__device__ inline void gll16(const void* g, void* l) {
    __builtin_amdgcn_global_load_lds(
        (const __attribute__((address_space(1))) void*)g,
        (__attribute__((address_space(3))) void*)l, 16, 0, 0);
}

// ---------------------------------------------------------------------------
// bf16 MFMA GEMM: C = op(A) @ Wt^T + bias [+ Cadd]
//   BK=64: halves barrier count per block (K only 128/256). LDS 35KB.
//   op: if isum: a = relu(a*sc[k] + sh[k]) with sc/sh computed IN-BLOCK from
//       raw BN sums (bn_finalize fused). Transform path stages A via VGPR.
//   Non-transform A and ALL B tiles stage via global_load_lds (16B/lane).
//   if ssum: per-column sum/sumsq of f32 output via LDS reduce + global atomic
// 128x128 tile, 256 thr = 4 waves, each wave 64x64 via 32 MFMA/K-step.
// ---------------------------------------------------------------------------
__global__ __launch_bounds__(256) void gemm_b(
    const u16* __restrict__ A, const u16* __restrict__ Bt,
    const float* __restrict__ bias,
    const float* __restrict__ isum, const float* __restrict__ isq,
    const float* __restrict__ ig, const float* __restrict__ ibe, float iminv,
    const u16* __restrict__ Cadd, u16* __restrict__ C,
    int M, int K, int Ntot,
    float* __restrict__ ssum, float* __restrict__ ssq)
{
    __shared__ u16 As[8 * 128 * 8];   // [k8 0..7][row][j]
    __shared__ u16 Bs[8 * 128 * 8];
    __shared__ float ls[128], lq[128];
    __shared__ float sIsc[256], sIsh[256];
    const int tid  = threadIdx.x;
    const int wave = tid >> 6, lane = tid & 63;
    const int quad = lane >> 4, l15 = lane & 15;
    const int wm = (wave & 1) * 64, wn = (wave >> 1) * 64;
    const int m0 = blockIdx.y * 128, n0 = blockIdx.x * 128;
    const int r  = tid >> 1;           // 0..127 tile row (transform path)
    const int g0 = (tid & 1) * 4;      // k8-group base (transform path)

    if (isum) {   // fused bn_finalize: raw sums -> per-channel scale/shift
        if (tid < K) {
            float mu = isum[tid] * iminv;
            float va = fmaxf(isq[tid] * iminv - mu * mu, 0.f);
            float s  = ig[tid] * rsqrtf(va + 1e-5f);
            sIsc[tid] = s;
            sIsh[tid] = fmaf(-mu, s, ibe[tid]);
        }
        __syncthreads();
    }

    f32x4 acc[4][4];
#pragma unroll
    for (int i = 0; i < 4; ++i)
#pragma unroll
        for (int j = 0; j < 4; ++j) acc[i][j] = (f32x4)0.f;

    const int m = m0 + r;
    for (int k0 = 0; k0 < K; k0 += 64) {
        if (isum) {
            // transform path: VGPR staging + relu(sc*a+sh), zero-fill OOB
#pragma unroll
            for (int j = 0; j < 4; ++j) {
                const int cg = g0 + j;
                uint4 av = make_uint4(0, 0, 0, 0);
                if (m < M) av = *(const uint4*)(A + (size_t)m * K + k0 + cg * 8);
                u32* w = (u32*)&av;
#pragma unroll
                for (int q2 = 0; q2 < 4; ++q2) {
                    int kk = k0 + cg * 8 + q2 * 2;
                    float2 f = up2(w[q2]);
                    f.x = fmaxf(fmaf(f.x, sIsc[kk],     sIsh[kk]),     0.f);
                    f.y = fmaxf(fmaf(f.y, sIsc[kk + 1], sIsh[kk + 1]), 0.f);
                    w[q2] = pk2(f.x, f.y);
                }
                *(uint4*)&As[(cg * 128 + r) * 8] = av;
            }
        } else {
            // direct HBM->LDS: wave w covers k8-groups w and w+4
#pragma unroll
            for (int kk = 0; kk < 2; ++kk)
#pragma unroll
                for (int j = 0; j < 2; ++j)
                    gll16(A + (size_t)(m0 + j * 64 + lane) * K + k0 + (wave + kk * 4) * 8,
                          &As[((wave + kk * 4) * 128 + j * 64) * 8]);
        }
#pragma unroll
        for (int kk = 0; kk < 2; ++kk)
#pragma unroll
            for (int j = 0; j < 2; ++j)
                gll16(Bt + (size_t)(n0 + j * 64 + lane) * K + k0 + (wave + kk * 4) * 8,
                      &Bs[((wave + kk * 4) * 128 + j * 64) * 8]);
        __syncthreads();

#pragma unroll
        for (int kk = 0; kk < 2; ++kk) {
            s16x8 a[4], b[4];
#pragma unroll
            for (int mi = 0; mi < 4; ++mi)
                a[mi] = *(const s16x8*)&As[((quad + kk * 4) * 128 + wm + mi * 16 + l15) * 8];
#pragma unroll
            for (int ni = 0; ni < 4; ++ni)
                b[ni] = *(const s16x8*)&Bs[((quad + kk * 4) * 128 + wn + ni * 16 + l15) * 8];
#pragma unroll
            for (int mi = 0; mi < 4; ++mi)
#pragma unroll
                for (int ni = 0; ni < 4; ++ni)
                    acc[mi][ni] = __builtin_amdgcn_mfma_f32_16x16x32_bf16(
                        a[mi], b[ni], acc[mi][ni], 0, 0, 0);
        }
        __syncthreads();
    }

    if (ssum) {
        if (tid < 128) { ls[tid] = 0.f; lq[tid] = 0.f; }
        __syncthreads();
    }

    float cs[4] = {0.f, 0.f, 0.f, 0.f}, cq[4] = {0.f, 0.f, 0.f, 0.f};
#pragma unroll
    for (int mi = 0; mi < 4; ++mi) {
        int rowb = m0 + wm + mi * 16 + quad * 4;
#pragma unroll
        for (int ni = 0; ni < 4; ++ni) {
            int col = n0 + wn + ni * 16 + l15;
            float bv = bias[col];
#pragma unroll
            for (int rr = 0; rr < 4; ++rr) {
                int row = rowb + rr;
                if (row < M) {
                    float v = acc[mi][ni][rr] + bv;
                    size_t idx = (size_t)row * Ntot + col;
                    if (Cadd) v += bf2f(Cadd[idx]);
                    C[idx] = f2bf(v);
                    cs[ni] += v;
                    cq[ni] = fmaf(v, v, cq[ni]);
                }
            }
        }
    }

    if (ssum) {
#pragma unroll
        for (int ni = 0; ni < 4; ++ni) {
            int lc = wn + ni * 16 + l15;    // 0..127 within block
            atomicAdd(&ls[lc], cs[ni]);
            atomicAdd(&lq[lc], cq[ni]);
        }
        __syncthreads();
        if (tid < 128) {
            atomicAdd(&ssum[n0 + tid], ls[tid]);
            atomicAdd(&ssq[n0 + tid], lq[tid]);
        }
    }
}

static inline void gemm_launch(hipStream_t s, const u16* A, const u16* Bt,
    const float* bias,
    const float* isum, const float* isq, const float* ig, const float* ibe,
    float iminv, const u16* Cadd, u16* C, int M, int K, int Ntot,
    float* ssum = nullptr, float* ssq = nullptr)
{
    dim3 grid(Ntot / 128, (M + 127) / 128);
    gemm_b<<<grid, dim3(256), 0, s>>>(A, Bt, bias, isum, isq, ig, ibe, iminv,
                                      Cadd, C, M, K, Ntot, ssum, ssq);
}

// fp32 [M,K] -> bf16 [M,Kp] zero-padded  (Kp2 = Kp/2 u32 per row)
__global__ void cvt_pad(const float* __restrict__ src, u32* __restrict__ dst,
                        int M, int K, int Kp2)
{
    int idx = blockIdx.x * 256 + threadIdx.x;
    if (idx >= M * Kp2) return;
    int row = idx / Kp2, c = (idx - row * Kp2) * 2;
    float a = (c < K)     ? src[(size_t)row * K + c]     : 0.f;
    float b = (c + 1 < K) ? src[(size_t)row * K + c + 1] : 0.f;
    dst[idx] = pk2(a, b);
}

// fp32 [M,K] gathered by CSR payload eid -> bf16 [M,Kp] in CSR order
__global__ void cvt_pad_perm(const float* __restrict__ src, const int2* __restrict__ csr2,
                             u32* __restrict__ dst, int M, int K, int Kp2)
{
    int idx = blockIdx.x * 256 + threadIdx.x;
    if (idx >= M * Kp2) return;
    int row = idx / Kp2, c = (idx - row * Kp2) * 2;
    int srow = csr2[row].x;
    float a = (c < K)     ? src[(size_t)srow * K + c]     : 0.f;
    float b = (c + 1 < K) ? src[(size_t)srow * K + c + 1] : 0.f;
    dst[idx] = pk2(a, b);
}

// fp32 [ne,11] gathered by CSR payload eid -> fp32 [ne,12] (16B rows) CSR order
__global__ void perm_attr12_k(const float* __restrict__ attr, const int2* __restrict__ csr2,
                              float* __restrict__ out, int ne)
{
    int idx = blockIdx.x * 256 + threadIdx.x;
    if (idx >= ne * 12) return;
    int e = idx / 12, k = idx - e * 12;
    int eid = csr2[e].x;
    out[idx] = (k < 11) ? attr[(size_t)eid * 11 + k] : 0.f;
}

// ---------------------------------------------------------------------------
// ALL weight preps in ONE launch
// ---------------------------------------------------------------------------
#define NJOBS 15
struct WtJobs {
    const float* W[NJOBS];
    u16* Wt[NJOBS];
    int K[NJOBS], N[NJOBS], Kp[NJOBS], end[NJOBS];   // end = exclusive prefix
};

__global__ void prep_wt_all(WtJobs jobs, int total)
{
    int idx = blockIdx.x * 256 + threadIdx.x;
    if (idx >= total) return;
    int j = 0;
    while (idx >= jobs.end[j]) ++j;
    int base = j ? jobs.end[j - 1] : 0;
    int loc = idx - base;
    int Kp = jobs.Kp[j];
    int n = loc / Kp, k = loc - n * Kp;
    jobs.Wt[j][loc] = (k < jobs.K[j])
        ? f2bf(jobs.W[j][(size_t)k * jobs.N[j] + n]) : (u16)0;
}

// ---------------------------------------------------------------------------
// CSR build: histogram -> 3-phase multi-block exclusive scan -> fill
// scan_emit writes start offsets into BOTH rowptr and cursor (same-thread
// read-then-write of deg/cursor -> no hazard), removing the D2D memcpy.
// ---------------------------------------------------------------------------
__global__ void hist_k(const int* __restrict__ idx, int n, int* __restrict__ deg)
{
    int i = blockIdx.x * 256 + threadIdx.x;
    if (i < n) atomicAdd(&deg[idx[i]], 1);
}

__global__ __launch_bounds__(256) void scan_part_k(const int* __restrict__ deg, int n,
                                                   int* __restrict__ bsum)
{
    __shared__ int ts[256];
    const int t = threadIdx.x;
    const int base = blockIdx.x * SC_CHUNK + t * 8;
    int s = 0;
#pragma unroll
    for (int j = 0; j < 8; ++j) { int i = base + j; if (i < n) s += deg[i]; }
    ts[t] = s;
    __syncthreads();
    for (int off = 128; off > 0; off >>= 1) {
        if (t < off) ts[t] += ts[t + off];
        __syncthreads();
    }
    if (t == 0) bsum[blockIdx.x] = ts[0];
}

__global__ __launch_bounds__(256) void scan_top_k(int* __restrict__ bsum, int nb)
{
    __shared__ int ss[256];
    const int t = threadIdx.x;
    int v = (t < nb) ? bsum[t] : 0;
    ss[t] = v;
    __syncthreads();
    for (int off = 1; off < 256; off <<= 1) {
        int u = (t >= off) ? ss[t - off] : 0;
        __syncthreads();
        ss[t] += u;
        __syncthreads();
    }
    if (t < nb) bsum[t] = ss[t] - v;   // exclusive
}

__global__ __launch_bounds__(256) void scan_emit_k(int* __restrict__ deg, int n,
                                                   const int* __restrict__ bsum,
                                                   int* __restrict__ rowptr)
{
    __shared__ int ts[256];
    const int t = threadIdx.x;
    const int base = blockIdx.x * SC_CHUNK + t * 8;
    int d[8], loc[8], s = 0;
#pragma unroll
    for (int j = 0; j < 8; ++j) {
        int i = base + j;
        d[j] = (i < n) ? deg[i] : 0;
        loc[j] = s;
        s += d[j];
    }
    ts[t] = s;
    __syncthreads();
    for (int off = 1; off < 256; off <<= 1) {
        int u = (t >= off) ? ts[t - off] : 0;
        __syncthreads();
        ts[t] += u;
        __syncthreads();
    }
    const int off0 = bsum[blockIdx.x] + (ts[t] - s);
#pragma unroll
    for (int j = 0; j < 8; ++j) {
        int i = base + j;
        if (i < n) {
            int st = off0 + loc[j];
            rowptr[i] = st;
            deg[i] = st;            // cursor copy (deg/cursor is same buffer)
            if (i == n - 1) rowptr[n] = st + d[j];
        }
    }
}

static void csr_prefix(hipStream_t s, const int* idx, int ne, int nbkt,
                       int* rowptr, int* cursor, int* bsum)
{
    hipMemsetAsync(cursor, 0, (size_t)nbkt * 4, s);
    hist_k<<<(ne + 255) / 256, 256, 0, s>>>(idx, ne, cursor);
    int nblk = (nbkt + SC_CHUNK - 1) / SC_CHUNK;
    scan_part_k<<<nblk, 256, 0, s>>>(cursor, nbkt, bsum);
    scan_top_k<<<1, 256, 0, s>>>(bsum, nblk);
    scan_emit_k<<<nblk, 256, 0, s>>>(cursor, nbkt, bsum, rowptr);
}

// payload = (edge id, src[edge id])
__global__ void fill2_k(const int* __restrict__ idx, const int* __restrict__ src,
                        int n, int* __restrict__ cursor, int2* __restrict__ csr2)
{
    int i = blockIdx.x * 256 + threadIdx.x;
    if (i < n) {
        int p = atomicAdd(&cursor[idx[i]], 1);
        csr2[p] = make_int2(i, src[i]);
    }
}

// payload = map[i] (or i if map==nullptr)
__global__ void fillm_k(const int* __restrict__ idx, const int* __restrict__ map,
                        int n, int* __restrict__ cursor, int* __restrict__ csr)
{
    int i = blockIdx.x * 256 + threadIdx.x;
    if (i < n) {
        int p = atomicAdd(&cursor[idx[i]], 1);
        csr[p] = map ? map[i] : i;
    }
}

// per-lane BN coefficients from raw sums (bn_finalize fused into consumers)
__device__ inline void bn_lane(const float* bsum, const float* bsq,
                               const float* bg, const float* bbe, float minv,
                               int lane, float& sc0, float& sc1, float& sh0, float& sh1)
{
    float mu0 = bsum[2 * lane] * minv,     mu1 = bsum[2 * lane + 1] * minv;
    float va0 = fmaxf(bsq[2 * lane] * minv - mu0 * mu0, 0.f);
    float va1 = fmaxf(bsq[2 * lane + 1] * minv - mu1 * mu1, 0.f);
    sc0 = bg[2 * lane] * rsqrtf(va0 + 1e-5f);
    sc1 = bg[2 * lane + 1] * rsqrtf(va1 + 1e-5f);
    sh0 = fmaf(-mu0, sc0, bbe[2 * lane]);
    sh1 = fmaf(-mu1, sc1, bbe[2 * lane + 1]);
}

// ---------------------------------------------------------------------------
// Atom GINE aggregation, STREAMING + DEPTH-2 x-gather pipeline:
//   x[src(e)] issued 2 iterations before use; payload chain runs 4 ahead so
//   the gather always uses a resident payload. attr stays depth-1 (sequential
//   stream, L2-friendly). All pipeline state in NAMED registers.
// ---------------------------------------------------------------------------
__global__ __launch_bounds__(256) void gine_agg_atom_b(
    const u32* __restrict__ x2, const float4* __restrict__ attrp,
    const int2* __restrict__ csr2, const int* __restrict__ rowptr,
    const float* __restrict__ Wm, const float* __restrict__ bm,
    const float* __restrict__ bsum, const float* __restrict__ bsq,
    const float* __restrict__ bg, const float* __restrict__ bbe,
    float bminv, int trelu,
    u32* __restrict__ out2, int n)
{
    const int lane = threadIdx.x & 63;
    const int v0 = (blockIdx.x * 4 + (threadIdx.x >> 6)) * NPW;
    if (v0 >= n) return;
    const int vend = (v0 + NPW < n) ? v0 + NPW : n;

    const float2 w0 = *(const float2*)&Wm[0 * 128 + 2 * lane];
    const float2 w1 = *(const float2*)&Wm[1 * 128 + 2 * lane];
    const float2 w2 = *(const float2*)&Wm[2 * 128 + 2 * lane];
    const float2 w3 = *(const float2*)&Wm[3 * 128 + 2 * lane];
    const float2 w4 = *(const float2*)&Wm[4 * 128 + 2 * lane];
    const float2 w5 = *(const float2*)&Wm[5 * 128 + 2 * lane];
    const float2 w6 = *(const float2*)&Wm[6 * 128 + 2 * lane];
    const float2 w7 = *(const float2*)&Wm[7 * 128 + 2 * lane];
    const float2 w8 = *(const float2*)&Wm[8 * 128 + 2 * lane];
    const float2 w9 = *(const float2*)&Wm[9 * 128 + 2 * lane];
    const float2 wa = *(const float2*)&Wm[10 * 128 + 2 * lane];
    const float2 bb = *(const float2*)&bm[2 * lane];

    float sc0 = 1.f, sc1 = 1.f, sh0 = 0.f, sh1 = 0.f;
    if (bsum) bn_lane(bsum, bsq, bg, bbe, bminv, lane, sc0, sc1, sh0, sh1);

    const int E0 = rowptr[v0], E1 = rowptr[vend];
    int v  = v0;
    int nb = rowptr[v0 + 1];
    u32 xs_n = (v0 + 1 < vend) ? x2[(size_t)(v0 + 1) * 64 + lane] : 0u;
    float2 acc = up2(x2[(size_t)v0 * 64 + lane]);
    acc.x = fmaf(acc.x, sc0, sh0); acc.y = fmaf(acc.y, sc1, sh1);
    if (trelu) { acc.x = fmaxf(acc.x, 0.f); acc.y = fmaxf(acc.y, 0.f); }

    if (E0 < E1) {
        // prologue: x depth-2 (xc=e, x1=e+1 in flight), payload chain to e+3
        int2 p0 = csr2[E0];
        u32  xc = x2[(size_t)p0.y * 64 + lane];
        int2 p1 = csr2[(E0 + 1 < E1) ? E0 + 1 : E0];
        u32  x1 = x2[(size_t)p1.y * 64 + lane];
        int2 pC = csr2[(E0 + 2 < E1) ? E0 + 2 : E0];   // payload(e+2)
        int2 pD = csr2[(E0 + 3 < E1) ? E0 + 3 : E0];   // payload(e+3)
        float4 a0c = attrp[3 * (size_t)E0];
        float4 a1c = attrp[3 * (size_t)E0 + 1];
        float4 a2c = attrp[3 * (size_t)E0 + 2];
        for (int e = E0; e < E1; ++e) {
            const int en = (e + 1 < E1) ? e + 1 : e;
            const int e4 = (e + 4 < E1) ? e + 4 : en;
            int2 pE = csr2[e4];                       // payload 4 ahead
            u32  xN = x2[(size_t)pC.y * 64 + lane];   // x for e+2 (2-iter cover)
            float4 a0n = attrp[3 * (size_t)en];
            float4 a1n = attrp[3 * (size_t)en + 1];
            float4 a2n = attrp[3 * (size_t)en + 2];
            // flush completed node(s) — wave-uniform branch
            while (e >= nb) {
                out2[(size_t)v * 64 + lane] = pk2(acc.x, acc.y);
                ++v;
                float2 nx = up2(xs_n);
                nx.x = fmaf(nx.x, sc0, sh0); nx.y = fmaf(nx.y, sc1, sh1);
                if (trelu) { nx.x = fmaxf(nx.x, 0.f); nx.y = fmaxf(nx.y, 0.f); }
                acc = nx;
                xs_n = (v + 1 < vend) ? x2[(size_t)(v + 1) * 64 + lane] : xs_n;
                nb = rowptr[v + 1];
            }
            // compute edge e (all operands resident, named regs only)
            float m0 = bb.x, m1 = bb.y;
            m0 = fmaf(a0c.x, w0.x, m0); m1 = fmaf(a0c.x, w0.y, m1);
            m0 = fmaf(a0c.y, w1.x, m0); m1 = fmaf(a0c.y, w1.y, m1);
            m0 = fmaf(a0c.z, w2.x, m0); m1 = fmaf(a0c.z, w2.y, m1);
            m0 = fmaf(a0c.w, w3.x, m0); m1 = fmaf(a0c.w, w3.y, m1);
            m0 = fmaf(a1c.x, w4.x, m0); m1 = fmaf(a1c.x, w4.y, m1);
            m0 = fmaf(a1c.y, w5.x, m0); m1 = fmaf(a1c.y, w5.y, m1);
            m0 = fmaf(a1c.z, w6.x, m0); m1 = fmaf(a1c.z, w6.y, m1);
            m0 = fmaf(a1c.w, w7.x, m0); m1 = fmaf(a1c.w, w7.y, m1);
            m0 = fmaf(a2c.x, w8.x, m0); m1 = fmaf(a2c.x, w8.y, m1);
            m0 = fmaf(a2c.y, w9.x, m0); m1 = fmaf(a2c.y, w9.y, m1);
            m0 = fmaf(a2c.z, wa.x, m0); m1 = fmaf(a2c.z, wa.y, m1);
            float2 s = up2(xc);
            s.x = fmaf(s.x, sc0, sh0); s.y = fmaf(s.y, sc1, sh1);
            if (trelu) { s.x = fmaxf(s.x, 0.f); s.y = fmaxf(s.y, 0.f); }
            acc.x += fmaxf(s.x + m0, 0.f);
            acc.y += fmaxf(s.y + m1, 0.f);
            // rotate pipeline
            xc = x1; x1 = xN;
            pC = pD; pD = pE;
            a0c = a0n; a1c = a1n; a2c = a2n;
        }
    }
    // tail flush: nodes v .. vend-1
    for (;;) {
        out2[(size_t)v * 64 + lane] = pk2(acc.x, acc.y);
        ++v;
        if (v >= vend) break;
        float2 nx = up2(xs_n);
        nx.x = fmaf(nx.x, sc0, sh0); nx.y = fmaf(nx.y, sc1, sh1);
        if (trelu) { nx.x = fmaxf(nx.x, 0.f); nx.y = fmaxf(nx.y, 0.f); }
        acc = nx;
        xs_n = (v + 1 < vend) ? x2[(size_t)(v + 1) * 64 + lane] : xs_n;
    }
}

// fg aggregation, STREAMING depth-1 (R9-verified); eemb2 CSR-ORDERED.
__global__ __launch_bounds__(256) void gine_agg_pre_b(
    const u32* __restrict__ x2, const u32* __restrict__ eemb2,
    const int2* __restrict__ csr2, const int* __restrict__ rowptr,
    const float* __restrict__ bsum, const float* __restrict__ bsq,
    const float* __restrict__ bg, const float* __restrict__ bbe,
    float bminv, int trelu,
    u32* __restrict__ out2, int n)
{
    const int lane = threadIdx.x & 63;
    const int v0 = (blockIdx.x * 4 + (threadIdx.x >> 6)) * NPW;
    if (v0 >= n) return;
    const int vend = (v0 + NPW < n) ? v0 + NPW : n;

    float sc0 = 1.f, sc1 = 1.f, sh0 = 0.f, sh1 = 0.f;
    if (bsum) bn_lane(bsum, bsq, bg, bbe, bminv, lane, sc0, sc1, sh0, sh1);

    const int E0 = rowptr[v0], E1 = rowptr[vend];
    int v  = v0;
    int nb = rowptr[v0 + 1];
    u32 xs_n = (v0 + 1 < vend) ? x2[(size_t)(v0 + 1) * 64 + lane] : 0u;
    float2 acc = up2(x2[(size_t)v0 * 64 + lane]);
    acc.x = fmaf(acc.x, sc0, sh0); acc.y = fmaf(acc.y, sc1, sh1);
    if (trelu) { acc.x = fmaxf(acc.x, 0.f); acc.y = fmaxf(acc.y, 0.f); }

    if (E0 < E1) {
        int2 pc = csr2[E0];
        int2 pn = csr2[(E0 + 1 < E1) ? E0 + 1 : E0];
        u32 xc = x2[(size_t)pc.y * 64 + lane];
        u32 mc = eemb2[(size_t)E0 * 64 + lane];
        for (int e = E0; e < E1; ++e) {
            const int en  = (e + 1 < E1) ? e + 1 : e;
            const int en2 = (e + 2 < E1) ? e + 2 : en;
            int2 p2 = csr2[en2];
            u32 xn = x2[(size_t)pn.y * 64 + lane];
            u32 mn = eemb2[(size_t)en * 64 + lane];
            while (e >= nb) {
                out2[(size_t)v * 64 + lane] = pk2(acc.x, acc.y);
                ++v;
                float2 nx = up2(xs_n);
                nx.x = fmaf(nx.x, sc0, sh0); nx.y = fmaf(nx.y, sc1, sh1);
                if (trelu) { nx.x = fmaxf(nx.x, 0.f); nx.y = fmaxf(nx.y, 0.f); }
                acc = nx;
                xs_n = (v + 1 < vend) ? x2[(size_t)(v + 1) * 64 + lane] : xs_n;
                nb = rowptr[v + 1];
            }
            float2 m = up2(mc);
            float2 s = up2(xc);
            s.x = fmaf(s.x, sc0, sh0); s.y = fmaf(s.y, sc1, sh1);
            if (trelu) { s.x = fmaxf(s.x, 0.f); s.y = fmaxf(s.y, 0.f); }
            acc.x += fmaxf(m.x + s.x, 0.f);
            acc.y += fmaxf(m.y + s.y, 0.f);
            pn = p2; xc = xn; mc = mn;
        }
    }
    for (;;) {
        out2[(size_t)v * 64 + lane] = pk2(acc.x, acc.y);
        ++v;
        if (v >= vend) break;
        float2 nx = up2(xs_n);
        nx.x = fmaf(nx.x, sc0, sh0); nx.y = fmaf(nx.y, sc1, sh1);
        if (trelu) { nx.x = fmaxf(nx.x, 0.f); nx.y = fmaxf(nx.y, 0.f); }
        acc = nx;
        xs_n = (v + 1 < vend) ? x2[(size_t)(v + 1) * 64 + lane] : xs_n;
    }
}

// segment mean, bf16 -> bf16; post-mean affine from raw sums (empty seg -> 0)
__global__ __launch_bounds__(256) void seg_mean_b2b(
    const u32* __restrict__ x2, const int* __restrict__ csr,
    const int* __restrict__ rowptr,
    const float* __restrict__ bsum, const float* __restrict__ bsq,
    const float* __restrict__ bg, const float* __restrict__ bbe, float bminv,
    u32* __restrict__ out2, int n)
{
    const int lane = threadIdx.x & 63;
    const int v = blockIdx.x * 4 + (threadIdx.x >> 6);
    if (v >= n) return;
    const int e0 = rowptr[v], e1 = rowptr[v + 1];
    float2 acc = make_float2(0.f, 0.f);
    if (e0 < e1) {
        int cc = csr[e0];
        int cn = csr[(e0 + 1 < e1) ? e0 + 1 : e0];
        u32 xc = x2[(size_t)cc * 64 + lane];
        for (int e = e0; e < e1; ++e) {
            const int en  = (e + 1 < e1) ? e + 1 : e;
            const int en2 = (e + 2 < e1) ? e + 2 : en;
            int c2 = csr[en2];
            u32 xn = x2[(size_t)cn * 64 + lane];
            float2 s = up2(xc);
            acc.x += s.x; acc.y += s.y;
            cn = c2; xc = xn;
        }
    }
    float inv = 1.f / fmaxf((float)(e1 - e0), 1.f);
    float2 r = make_float2(acc.x * inv, acc.y * inv);
    if (bsum) {
        if (e1 > e0) {
            float sc0, sc1, sh0, sh1;
            bn_lane(bsum, bsq, bg, bbe, bminv, lane, sc0, sc1, sh0, sh1);
            r.x = fmaf(r.x, sc0, sh0);
            r.y = fmaf(r.y, sc1, sh1);
        } else {
            r.x = 0.f; r.y = 0.f;
        }
    }
    out2[(size_t)v * 64 + lane] = pk2(r.x, r.y);
}

// segment mean, bf16 -> fp32 (final), same post-mean affine
__global__ __launch_bounds__(256) void seg_mean_b2f(
    const u32* __restrict__ x2, const int* __restrict__ csr,
    const int* __restrict__ rowptr,
    const float* __restrict__ bsum, const float* __restrict__ bsq,
    const float* __restrict__ bg, const float* __restrict__ bbe, float bminv,
    float* __restrict__ out, int n)
{
    const int lane = threadIdx.x & 63;
    const int v = blockIdx.x * 4 + (threadIdx.x >> 6);
    if (v >= n) return;
    const int e0 = rowptr[v], e1 = rowptr[v + 1];
    float2 acc = make_float2(0.f, 0.f);
    if (e0 < e1) {
        int cc = csr[e0];
        int cn = csr[(e0 + 1 < e1) ? e0 + 1 : e0];
        u32 xc = x2[(size_t)cc * 64 + lane];
        for (int e = e0; e < e1; ++e) {
            const int en  = (e + 1 < e1) ? e + 1 : e;
            const int en2 = (e + 2 < e1) ? e + 2 : en;
            int c2 = csr[en2];
            u32 xn = x2[(size_t)cn * 64 + lane];
            float2 s = up2(xc);
            acc.x += s.x; acc.y += s.y;
            cn = c2; xc = xn;
        }
    }
    float inv = 1.f / fmaxf((float)(e1 - e0), 1.f);
    float2 r = make_float2(acc.x * inv, acc.y * inv);
    if (bsum) {
        if (e1 > e0) {
            float sc0, sc1, sh0, sh1;
            bn_lane(bsum, bsq, bg, bbe, bminv, lane, sc0, sc1, sh0, sh1);
            r.x = fmaf(r.x, sc0, sh0);
            r.y = fmaf(r.y, sc1, sh1);
        } else {
            r.x = 0.f; r.y = 0.f;
        }
    }
    *(float2*)&out[(size_t)v * 128 + lane * 2] = r;
}

// ---------------------------------------------------------------------------
extern "C" void kernel_launch(void* const* d_in, const int* in_sizes, int n_in,
                              void* d_out, int out_size, void* d_ws, size_t ws_size,
                              hipStream_t stream)
{
    const float* atom_x        = (const float*)d_in[0];
    const float* fg_x          = (const float*)d_in[1];
    const float* atom_edge_attr= (const float*)d_in[2];
    const float* fg_edge_attr  = (const float*)d_in[3];
    const float* atom_emb_W    = (const float*)d_in[4];
    const float* atom_emb_b    = (const float*)d_in[5];
    const float* fg_emb_W      = (const float*)d_in[6];
    const float* fg_emb_b      = (const float*)d_in[7];
    const float* bond_W        = (const float*)d_in[8];
    const float* bond_b        = (const float*)d_in[9];
    const float* ag_W1         = (const float*)d_in[10];
    const float* ag_b1         = (const float*)d_in[11];
    const float* ag_g1         = (const float*)d_in[12];
    const float* ag_be1        = (const float*)d_in[13];
    const float* ag_W2         = (const float*)d_in[14];
    const float* ag_b2         = (const float*)d_in[15];
    const float* abn_g         = (const float*)d_in[16];
    const float* abn_b         = (const float*)d_in[17];
    const float* fge_W         = (const float*)d_in[18];
    const float* fge_b         = (const float*)d_in[19];
    const float* fg_W1         = (const float*)d_in[20];
    const float* fg_b1         = (const float*)d_in[21];
    const float* fg_g1         = (const float*)d_in[22];
    const float* fg_be1        = (const float*)d_in[23];
    const float* fg_W2         = (const float*)d_in[24];
    const float* fg_b2         = (const float*)d_in[25];
    const float* fbn_g         = (const float*)d_in[26];
    const float* fbn_b         = (const float*)d_in[27];
    const float* a2f_W         = (const float*)d_in[28];
    const float* a2f_b         = (const float*)d_in[29];
    const int*   aei           = (const int*)d_in[30];
    const int*   fei           = (const int*)d_in[31];
    const int*   atom_idx      = (const int*)d_in[32];
    const int*   fg_idx        = (const int*)d_in[33];
    const int*   fg_batch      = (const int*)d_in[34];
    const int *asrc = aei, *adst = aei + EA_C;
    const int *fsrc = fei, *fdst = fei + EF_C;

    // ---- workspace carving (bytes) ----
    char* base = (char*)d_ws;
    const size_t SZ_H = (size_t)NA_C * DD * 2;        // 51.2 MB bf16 node slot
    u16* hA = (u16*)base;                             // h ping
    u16* hB = (u16*)(base + SZ_H);                    // h pong
    u16* TB = (u16*)(base + 2 * SZ_H);                // t (NA x 256 bf16, 102.4 MB)
    u16* XB = (u16*)(base + 2 * SZ_H + (size_t)NA_C * HH * 2);  // atom_x_bf / attr_perm / fg_attr_bf
    char* csrb = (char*)XB + SZ_H;                    // CSR area (16B aligned)
    int*  aR  = (int*)csrb;                           // rowptr (max NA+1)
    int*  aCu = aR + (NA_C + 2);                      // cursor/deg (max NA)
    int*  bS  = aCu + NA_C;                           // scan partials (256)
    int2* aE2 = (int2*)(bS + 258);                    // payload (max EA int2)
    char* wtb = (char*)(aE2 + EA_C);
    wtb = (char*)(((uintptr_t)wtb + 15) & ~(uintptr_t)15);   // 16B align
    u16* WT_aemb = (u16*)wtb;                 wtb += 128 * 128 * 2;
    u16* WT_aW1  = (u16*)wtb;                 wtb += 3 * 256 * 128 * 2;
    u16* WT_aW2  = (u16*)wtb;                 wtb += 3 * 128 * 256 * 2;
    u16* WT_a2f  = (u16*)wtb;                 wtb += 128 * 128 * 2;
    u16* WT_femb = (u16*)wtb;                 wtb += 128 * 128 * 2;   // Kp=128
    u16* WT_fge  = (u16*)wtb;                 wtb += 2 * 128 * 128 * 2;
    u16* WT_fW1  = (u16*)wtb;                 wtb += 2 * 256 * 128 * 2;
    u16* WT_fW2  = (u16*)wtb;                 wtb += 2 * 128 * 256 * 2;
    // per-stage BN stats arena: 10 stages x {sum,sq} x 256 floats, zeroed once
    float* stats = (float*)wtb;               wtb += 5120 * sizeof(float);
    float* S_SUM = stats;            // + st*256
    float* S_SQ  = stats + 2560;

    // ---- ALL weight preps in one launch ----
    {
        WtJobs jb;
        int t = 0, acc = 0;
        auto add = [&](const float* W, u16* Wt, int K, int N, int Kp) {
            jb.W[t] = W; jb.Wt[t] = Wt; jb.K[t] = K; jb.N[t] = N; jb.Kp[t] = Kp;
            acc += N * Kp; jb.end[t] = acc; ++t;
        };
        add(atom_emb_W, WT_aemb, 101, 128, 128);
        add(a2f_W,      WT_a2f,  128, 128, 128);
        for (int i = 0; i < 3; ++i)
            add(ag_W1 + (size_t)i * 128 * 256, WT_aW1 + (size_t)i * 256 * 128, 128, 256, 128);
        for (int i = 0; i < 3; ++i)
            add(ag_W2 + (size_t)i * 256 * 128, WT_aW2 + (size_t)i * 128 * 256, 256, 128, 256);
        add(fg_emb_W,   WT_femb, 73, 128, 128);   // Kp padded 96 -> 128 (BK=64)
        for (int i = 0; i < 2; ++i)
            add(fge_W + (size_t)i * 101 * 128, WT_fge + (size_t)i * 128 * 128, 101, 128, 128);
        for (int i = 0; i < 2; ++i)
            add(fg_W1 + (size_t)i * 128 * 256, WT_fW1 + (size_t)i * 256 * 128, 128, 256, 128);
        for (int i = 0; i < 2; ++i)
            add(fg_W2 + (size_t)i * 256 * 128, WT_fW2 + (size_t)i * 128 * 256, 256, 128, 256);
        prep_wt_all<<<(acc + 255) / 256, 256, 0, stream>>>(jb, acc);
    }
    hipMemsetAsync(stats, 0, 5120 * sizeof(float), stream);   // all sums+sqs

    // ---- atom CSR (dst-sorted, payload (eid, src)) ----
    csr_prefix(stream, adst, EA_C, NA_C, aR, aCu, bS);
    fill2_k<<<(EA_C + 255) / 256, 256, 0, stream>>>(adst, asrc, EA_C, aCu, aE2);

    // ---- atom_x -> bf16 padded [NA,128] (XB) ----
    cvt_pad<<<((size_t)NA_C * 64 + 255) / 256, 256, 0, stream>>>(atom_x, (u32*)XB, NA_C, 101, 64);

    // ---- atom embedding (consumes XB) ----
    gemm_launch(stream, XB, WT_aemb, atom_emb_b,
                nullptr, nullptr, nullptr, nullptr, 0.f, nullptr, hA, NA_C, 128, 128);

    // ---- attr -> CSR-permuted [EA,12] fp32 (reuses XB) ----
    float* attrP = (float*)XB;
    perm_attr12_k<<<((size_t)EA_C * 12 + 255) / 256, 256, 0, stream>>>(
        atom_edge_attr, aE2, attrP, EA_C);

    // ---- 3 atom GINE layers (hA <-> hB ping-pong) ----
    const int agrid = (NA_C + 4 * NPW - 1) / (4 * NPW);
    u16* hc = hA;
    const float* cb_sum = nullptr; const float* cb_sq = nullptr;
    const float* cb_g = nullptr;   const float* cb_be = nullptr;
    int cur_relu = 0;
    for (int i = 0; i < 3; ++i) {
        u16* hn = (hc == hA) ? hB : hA;
        const int st1 = 2 * i, st2 = 2 * i + 1;
        gine_agg_atom_b<<<agrid, 256, 0, stream>>>(
            (const u32*)hc, (const float4*)attrP, aE2, aR,
            bond_W + (size_t)i * 11 * DD, bond_b + i * DD,
            cb_sum, cb_sq, cb_g, cb_be, 1.f / NA_C, cur_relu, (u32*)hn, NA_C);
        gemm_launch(stream, hn, WT_aW1 + (size_t)i * 256 * 128,
                    ag_b1 + i * HH, nullptr, nullptr, nullptr, nullptr, 0.f,
                    nullptr, TB, NA_C, 128, HH,
                    S_SUM + st1 * 256, S_SQ + st1 * 256);
        gemm_launch(stream, TB, WT_aW2 + (size_t)i * 128 * 256,
                    ag_b2 + i * DD,
                    S_SUM + st1 * 256, S_SQ + st1 * 256,
                    ag_g1 + i * HH, ag_be1 + i * HH, 1.f / NA_C,
                    nullptr, hn, NA_C, 256, 128,
                    S_SUM + st2 * 256, S_SQ + st2 * 256);
        cb_sum = S_SUM + st2 * 256; cb_sq = S_SQ + st2 * 256;
        cb_g = abn_g + i * DD; cb_be = abn_b + i * DD;
        cur_relu = (i != 2);
        hc = hn;
    }
    // hc == hB (h3, raw); cb_* hold atom BN2[2] raw stats (affine, no relu)

    // ---- a2f: means = seg_mean(bn(h3)[atom_idx], fg_idx, NF) @ a2f_W + b ----
    {
        int* xE = (int*)aE2;
        csr_prefix(stream, fg_idx, NA_C, NF_C, aR, aCu, bS);
        fillm_k<<<(NA_C + 255) / 256, 256, 0, stream>>>(fg_idx, atom_idx, NA_C, aCu, xE);
        seg_mean_b2b<<<(NF_C + 3) / 4, 256, 0, stream>>>(
            (const u32*)hc, xE, aR, cb_sum, cb_sq, cb_g, cb_be, 1.f / NA_C,
            (u32*)hA, NF_C);
    }
    u16* means   = hA;                                  // [NF,128]
    u16* a2f_lin = hA + (size_t)NF_C * DD;              // [NF,128]
    gemm_launch(stream, means, WT_a2f, a2f_b,
                nullptr, nullptr, nullptr, nullptr, 0.f, nullptr, a2f_lin, NF_C, 128, 128);

    // ---- fg embedding: g = fg_x @ femb + b + a2f_lin  (K padded to 128) ----
    u16* fgx_bf = hA + 2 * (size_t)NF_C * DD;           // [NF,128]
    cvt_pad<<<((size_t)NF_C * 64 + 255) / 256, 256, 0, stream>>>(fg_x, (u32*)fgx_bf, NF_C, 73, 64);
    u16* g = hB;
    gemm_launch(stream, fgx_bf, WT_femb, fg_emb_b,
                nullptr, nullptr, nullptr, nullptr, 0.f, a2f_lin, g, NF_C, 128, 128);

    // ---- fg CSR FIRST, then fg edge attr -> bf16 [EF,128] in CSR order ----
    csr_prefix(stream, fdst, EF_C, NF_C, aR, aCu, bS);
    fill2_k<<<(EF_C + 255) / 256, 256, 0, stream>>>(fdst, fsrc, EF_C, aCu, aE2);
    cvt_pad_perm<<<((size_t)EF_C * 64 + 255) / 256, 256, 0, stream>>>(
        fg_edge_attr, aE2, (u32*)XB, EF_C, 101, 64);

    // ---- 2 fg GINE layers (g stored raw; consumer applies BN inline) ----
    const int fgrid = (NF_C + 4 * NPW - 1) / (4 * NPW);
    u16* eemb = TB;                                     // [EF,128] bf16
    u16* gn   = hA + 3 * (size_t)NF_C * DD;             // [NF,128]
    u16* gt   = TB + (size_t)EF_C * DD;                 // [NF,256]
    const float* gb_sum = nullptr; const float* gb_sq = nullptr;
    const float* gb_g = nullptr;   const float* gb_be = nullptr;
    int grelu = 0;
    for (int i = 0; i < 2; ++i) {
        const int st1 = 6 + 2 * i, st2 = 7 + 2 * i;
        gemm_launch(stream, XB, WT_fge + (size_t)i * 128 * 128,
                    fge_b + i * DD, nullptr, nullptr, nullptr, nullptr, 0.f,
                    nullptr, eemb, EF_C, 128, 128);
        gine_agg_pre_b<<<fgrid, 256, 0, stream>>>(
            (const u32*)g, (const u32*)eemb, aE2, aR,
            gb_sum, gb_sq, gb_g, gb_be, 1.f / NF_C, grelu, (u32*)gn, NF_C);
        gemm_launch(stream, gn, WT_fW1 + (size_t)i * 256 * 128,
                    fg_b1 + i * HH, nullptr, nullptr, nullptr, nullptr, 0.f,
                    nullptr, gt, NF_C, 128, HH,
                    S_SUM + st1 * 256, S_SQ + st1 * 256);
        gemm_launch(stream, gt, WT_fW2 + (size_t)i * 128 * 256,
                    fg_b2 + i * DD,
                    S_SUM + st1 * 256, S_SQ + st1 * 256,
                    fg_g1 + i * HH, fg_be1 + i * HH, 1.f / NF_C,
                    nullptr, g, NF_C, 256, 128,
                    S_SUM + st2 * 256, S_SQ + st2 * 256);
        gb_sum = S_SUM + st2 * 256; gb_sq = S_SQ + st2 * 256;
        gb_g = fbn_g + i * DD; gb_be = fbn_b + i * DD;
        grelu = (i != 1);
    }
    // gb_* hold fg BN2[1] raw stats (affine, no relu) -> applied post-mean

    // ---- final seg_mean(bn(g), fg_batch, NG) -> d_out fp32 ----
    {
        int* bR  = (int*)(gt + (size_t)NF_C * HH);
        int* bCu = bR + (NG_C + 1);
        int* bE  = bCu + NG_C;
        csr_prefix(stream, fg_batch, NF_C, NG_C, bR, bCu, bS);
        fillm_k<<<(NF_C + 255) / 256, 256, 0, stream>>>(fg_batch, nullptr, NF_C, bCu, bE);
        seg_mean_b2f<<<(NG_C + 3) / 4, 256, 0, stream>>>(
            (const u32*)g, bE, bR, gb_sum, gb_sq, gb_g, gb_be, 1.f / NF_C,
            (float*)d_out, NG_C);
    }
}

// Round 11
// 1881.522 us; speedup vs baseline: 1.1205x; 1.1205x over previous
//
#include <hip/hip_runtime.h>
#include <cstddef>
#include <cstdint>

#define NA_C 200000
#define NF_C 50000
#define EA_C 800000
#define EF_C 200000
#define NG_C 4096
#define DD 128
#define HH 256
#define SC_CHUNK 2048
#define NPW 8        // nodes per wave in streaming aggregation kernels

typedef unsigned short u16;
typedef unsigned int   u32;
typedef float f32x4 __attribute__((ext_vector_type(4)));
typedef short s16x8 __attribute__((ext_vector_type(8)));

__device__ inline float bf2f(u16 h) { return __uint_as_float(((u32)h) << 16); }
__device__ inline u16 f2bf(float f) {
    u32 u = __float_as_uint(f);
    return (u16)((u + 0x7fffu + ((u >> 16) & 1u)) >> 16);
}
__device__ inline float2 up2(u32 u) {
    return make_float2(__uint_as_float(u << 16), __uint_as_float(u & 0xffff0000u));
}
__device__ inline u32 pk2(float x, float y) { return (u32)f2bf(x) | ((u32)f2bf(y) << 16); }

// async global->LDS, 16B per lane; LDS dest = wave-uniform base + lane*16
__device__ inline void gll16(const void* g, void* l) {
    __builtin_amdgcn_global_load_lds(
        (const __attribute__((address_space(1))) void*)g,
        (__attribute__((address_space(3))) void*)l, 16, 0, 0);
}

// ---------------------------------------------------------------------------
// bf16 MFMA GEMM: C = op(A) @ Wt^T + bias [+ Cadd]
//   256x128 tile, BK=64, 512 thr = 8 waves (2 n-slices x 4 m-slices), each
//   wave the verified 64x64 microkernel. 2x work per block vs 128x128 ->
//   per-element barrier/prologue cost halves (thin-K GEMMs are
//   overhead-bound: K=128/256 means only 2-4 K-steps). LDS 52KB -> 3
//   blocks/CU = 24 waves/CU.
//   op: if isum: a = relu(a*sc[k] + sh[k]) with sc/sh computed IN-BLOCK from
//       raw BN sums (bn_finalize fused). Transform path stages A via VGPR
//       (load-guarded). Non-transform A and ALL B via global_load_lds;
//       A-tile OOB rows (<=192) read valid adjacent workspace (audited),
//       outputs row<M guarded.
//   if ssum: per-column sum/sumsq of f32 output via LDS reduce + global atomic
// ---------------------------------------------------------------------------
__global__ __launch_bounds__(512) void gemm_b(
    const u16* __restrict__ A, const u16* __restrict__ Bt,
    const float* __restrict__ bias,
    const float* __restrict__ isum, const float* __restrict__ isq,
    const float* __restrict__ ig, const float* __restrict__ ibe, float iminv,
    const u16* __restrict__ Cadd, u16* __restrict__ C,
    int M, int K, int Ntot,
    float* __restrict__ ssum, float* __restrict__ ssq)
{
    __shared__ u16 As[8 * 256 * 8];   // [k8 0..7][row 0..255][j]  32KB
    __shared__ u16 Bs[8 * 128 * 8];   // [k8 0..7][col 0..127][j]  16KB
    __shared__ float ls[128], lq[128];
    __shared__ float sIsc[256], sIsh[256];
    const int tid  = threadIdx.x;
    const int wave = tid >> 6, lane = tid & 63;
    const int quad = lane >> 4, l15 = lane & 15;
    const int wm = (wave & 3) * 64, wn = (wave >> 2) * 64;
    const int m0 = blockIdx.y * 256, n0 = blockIdx.x * 128;
    const int r  = tid >> 1;           // 0..255 tile row (transform path)
    const int g0 = (tid & 1) * 4;      // k8-group base (transform path)

    if (isum) {   // fused bn_finalize: raw sums -> per-channel scale/shift
        if (tid < K) {
            float mu = isum[tid] * iminv;
            float va = fmaxf(isq[tid] * iminv - mu * mu, 0.f);
            float s  = ig[tid] * rsqrtf(va + 1e-5f);
            sIsc[tid] = s;
            sIsh[tid] = fmaf(-mu, s, ibe[tid]);
        }
        __syncthreads();
    }

    f32x4 acc[4][4];
#pragma unroll
    for (int i = 0; i < 4; ++i)
#pragma unroll
        for (int j = 0; j < 4; ++j) acc[i][j] = (f32x4)0.f;

    for (int k0 = 0; k0 < K; k0 += 64) {
        if (isum) {
            // transform path: VGPR staging + relu(sc*a+sh), zero-fill OOB
            const int m = m0 + r;
#pragma unroll
            for (int j = 0; j < 4; ++j) {
                const int cg = g0 + j;
                uint4 av = make_uint4(0, 0, 0, 0);
                if (m < M) av = *(const uint4*)(A + (size_t)m * K + k0 + cg * 8);
                u32* w = (u32*)&av;
#pragma unroll
                for (int q2 = 0; q2 < 4; ++q2) {
                    int kk = k0 + cg * 8 + q2 * 2;
                    float2 f = up2(w[q2]);
                    f.x = fmaxf(fmaf(f.x, sIsc[kk],     sIsh[kk]),     0.f);
                    f.y = fmaxf(fmaf(f.y, sIsc[kk + 1], sIsh[kk + 1]), 0.f);
                    w[q2] = pk2(f.x, f.y);
                }
                *(uint4*)&As[(cg * 256 + r) * 8] = av;
            }
        } else {
            // direct HBM->LDS: wave w covers k8-group w, rowblocks 0..3
#pragma unroll
            for (int rb = 0; rb < 4; ++rb)
                gll16(A + (size_t)(m0 + rb * 64 + lane) * K + k0 + wave * 8,
                      &As[(wave * 256 + rb * 64) * 8]);
        }
        // Bs: wave w covers k8-group w, colblocks 0..1
#pragma unroll
        for (int cb = 0; cb < 2; ++cb)
            gll16(Bt + (size_t)(n0 + cb * 64 + lane) * K + k0 + wave * 8,
                  &Bs[(wave * 128 + cb * 64) * 8]);
        __syncthreads();

#pragma unroll
        for (int kk = 0; kk < 2; ++kk) {
            s16x8 a[4], b[4];
#pragma unroll
            for (int mi = 0; mi < 4; ++mi)
                a[mi] = *(const s16x8*)&As[((quad + kk * 4) * 256 + wm + mi * 16 + l15) * 8];
#pragma unroll
            for (int ni = 0; ni < 4; ++ni)
                b[ni] = *(const s16x8*)&Bs[((quad + kk * 4) * 128 + wn + ni * 16 + l15) * 8];
#pragma unroll
            for (int mi = 0; mi < 4; ++mi)
#pragma unroll
                for (int ni = 0; ni < 4; ++ni)
                    acc[mi][ni] = __builtin_amdgcn_mfma_f32_16x16x32_bf16(
                        a[mi], b[ni], acc[mi][ni], 0, 0, 0);
        }
        __syncthreads();
    }

    if (ssum) {
        if (tid < 128) { ls[tid] = 0.f; lq[tid] = 0.f; }
        __syncthreads();
    }

    float cs[4] = {0.f, 0.f, 0.f, 0.f}, cq[4] = {0.f, 0.f, 0.f, 0.f};
#pragma unroll
    for (int mi = 0; mi < 4; ++mi) {
        int rowb = m0 + wm + mi * 16 + quad * 4;
#pragma unroll
        for (int ni = 0; ni < 4; ++ni) {
            int col = n0 + wn + ni * 16 + l15;
            float bv = bias[col];
#pragma unroll
            for (int rr = 0; rr < 4; ++rr) {
                int row = rowb + rr;
                if (row < M) {
                    float v = acc[mi][ni][rr] + bv;
                    size_t idx = (size_t)row * Ntot + col;
                    if (Cadd) v += bf2f(Cadd[idx]);
                    C[idx] = f2bf(v);
                    cs[ni] += v;
                    cq[ni] = fmaf(v, v, cq[ni]);
                }
            }
        }
    }

    if (ssum) {
#pragma unroll
        for (int ni = 0; ni < 4; ++ni) {
            int lc = wn + ni * 16 + l15;    // 0..127 within block
            atomicAdd(&ls[lc], cs[ni]);
            atomicAdd(&lq[lc], cq[ni]);
        }
        __syncthreads();
        if (tid < 128) {
            atomicAdd(&ssum[n0 + tid], ls[tid]);
            atomicAdd(&ssq[n0 + tid], lq[tid]);
        }
    }
}

static inline void gemm_launch(hipStream_t s, const u16* A, const u16* Bt,
    const float* bias,
    const float* isum, const float* isq, const float* ig, const float* ibe,
    float iminv, const u16* Cadd, u16* C, int M, int K, int Ntot,
    float* ssum = nullptr, float* ssq = nullptr)
{
    dim3 grid(Ntot / 128, (M + 255) / 256);
    gemm_b<<<grid, dim3(512), 0, s>>>(A, Bt, bias, isum, isq, ig, ibe, iminv,
                                      Cadd, C, M, K, Ntot, ssum, ssq);
}

// fp32 [M,K] -> bf16 [M,Kp] zero-padded  (Kp2 = Kp/2 u32 per row)
__global__ void cvt_pad(const float* __restrict__ src, u32* __restrict__ dst,
                        int M, int K, int Kp2)
{
    int idx = blockIdx.x * 256 + threadIdx.x;
    if (idx >= M * Kp2) return;
    int row = idx / Kp2, c = (idx - row * Kp2) * 2;
    float a = (c < K)     ? src[(size_t)row * K + c]     : 0.f;
    float b = (c + 1 < K) ? src[(size_t)row * K + c + 1] : 0.f;
    dst[idx] = pk2(a, b);
}

// fp32 [M,K] gathered by CSR payload eid -> bf16 [M,Kp] in CSR order
__global__ void cvt_pad_perm(const float* __restrict__ src, const int2* __restrict__ csr2,
                             u32* __restrict__ dst, int M, int K, int Kp2)
{
    int idx = blockIdx.x * 256 + threadIdx.x;
    if (idx >= M * Kp2) return;
    int row = idx / Kp2, c = (idx - row * Kp2) * 2;
    int srow = csr2[row].x;
    float a = (c < K)     ? src[(size_t)srow * K + c]     : 0.f;
    float b = (c + 1 < K) ? src[(size_t)srow * K + c + 1] : 0.f;
    dst[idx] = pk2(a, b);
}

// fp32 [ne,11] gathered by CSR payload eid -> fp32 [ne,12] (16B rows) CSR order
__global__ void perm_attr12_k(const float* __restrict__ attr, const int2* __restrict__ csr2,
                              float* __restrict__ out, int ne)
{
    int idx = blockIdx.x * 256 + threadIdx.x;
    if (idx >= ne * 12) return;
    int e = idx / 12, k = idx - e * 12;
    int eid = csr2[e].x;
    out[idx] = (k < 11) ? attr[(size_t)eid * 11 + k] : 0.f;
}

// ---------------------------------------------------------------------------
// ALL weight preps in ONE launch
// ---------------------------------------------------------------------------
#define NJOBS 15
struct WtJobs {
    const float* W[NJOBS];
    u16* Wt[NJOBS];
    int K[NJOBS], N[NJOBS], Kp[NJOBS], end[NJOBS];   // end = exclusive prefix
};

__global__ void prep_wt_all(WtJobs jobs, int total)
{
    int idx = blockIdx.x * 256 + threadIdx.x;
    if (idx >= total) return;
    int j = 0;
    while (idx >= jobs.end[j]) ++j;
    int base = j ? jobs.end[j - 1] : 0;
    int loc = idx - base;
    int Kp = jobs.Kp[j];
    int n = loc / Kp, k = loc - n * Kp;
    jobs.Wt[j][loc] = (k < jobs.K[j])
        ? f2bf(jobs.W[j][(size_t)k * jobs.N[j] + n]) : (u16)0;
}

// ---------------------------------------------------------------------------
// CSR build: histogram -> 3-phase multi-block exclusive scan -> fill
// scan_emit writes start offsets into BOTH rowptr and cursor (same-thread
// read-then-write of deg/cursor -> no hazard), removing the D2D memcpy.
// ---------------------------------------------------------------------------
__global__ void hist_k(const int* __restrict__ idx, int n, int* __restrict__ deg)
{
    int i = blockIdx.x * 256 + threadIdx.x;
    if (i < n) atomicAdd(&deg[idx[i]], 1);
}

__global__ __launch_bounds__(256) void scan_part_k(const int* __restrict__ deg, int n,
                                                   int* __restrict__ bsum)
{
    __shared__ int ts[256];
    const int t = threadIdx.x;
    const int base = blockIdx.x * SC_CHUNK + t * 8;
    int s = 0;
#pragma unroll
    for (int j = 0; j < 8; ++j) { int i = base + j; if (i < n) s += deg[i]; }
    ts[t] = s;
    __syncthreads();
    for (int off = 128; off > 0; off >>= 1) {
        if (t < off) ts[t] += ts[t + off];
        __syncthreads();
    }
    if (t == 0) bsum[blockIdx.x] = ts[0];
}

__global__ __launch_bounds__(256) void scan_top_k(int* __restrict__ bsum, int nb)
{
    __shared__ int ss[256];
    const int t = threadIdx.x;
    int v = (t < nb) ? bsum[t] : 0;
    ss[t] = v;
    __syncthreads();
    for (int off = 1; off < 256; off <<= 1) {
        int u = (t >= off) ? ss[t - off] : 0;
        __syncthreads();
        ss[t] += u;
        __syncthreads();
    }
    if (t < nb) bsum[t] = ss[t] - v;   // exclusive
}

__global__ __launch_bounds__(256) void scan_emit_k(int* __restrict__ deg, int n,
                                                   const int* __restrict__ bsum,
                                                   int* __restrict__ rowptr)
{
    __shared__ int ts[256];
    const int t = threadIdx.x;
    const int base = blockIdx.x * SC_CHUNK + t * 8;
    int d[8], loc[8], s = 0;
#pragma unroll
    for (int j = 0; j < 8; ++j) {
        int i = base + j;
        d[j] = (i < n) ? deg[i] : 0;
        loc[j] = s;
        s += d[j];
    }
    ts[t] = s;
    __syncthreads();
    for (int off = 1; off < 256; off <<= 1) {
        int u = (t >= off) ? ts[t - off] : 0;
        __syncthreads();
        ts[t] += u;
        __syncthreads();
    }
    const int off0 = bsum[blockIdx.x] + (ts[t] - s);
#pragma unroll
    for (int j = 0; j < 8; ++j) {
        int i = base + j;
        if (i < n) {
            int st = off0 + loc[j];
            rowptr[i] = st;
            deg[i] = st;            // cursor copy (deg/cursor is same buffer)
            if (i == n - 1) rowptr[n] = st + d[j];
        }
    }
}

static void csr_prefix(hipStream_t s, const int* idx, int ne, int nbkt,
                       int* rowptr, int* cursor, int* bsum)
{
    hipMemsetAsync(cursor, 0, (size_t)nbkt * 4, s);
    hist_k<<<(ne + 255) / 256, 256, 0, s>>>(idx, ne, cursor);
    int nblk = (nbkt + SC_CHUNK - 1) / SC_CHUNK;
    scan_part_k<<<nblk, 256, 0, s>>>(cursor, nbkt, bsum);
    scan_top_k<<<1, 256, 0, s>>>(bsum, nblk);
    scan_emit_k<<<nblk, 256, 0, s>>>(cursor, nbkt, bsum, rowptr);
}

// payload = (edge id, src[edge id])
__global__ void fill2_k(const int* __restrict__ idx, const int* __restrict__ src,
                        int n, int* __restrict__ cursor, int2* __restrict__ csr2)
{
    int i = blockIdx.x * 256 + threadIdx.x;
    if (i < n) {
        int p = atomicAdd(&cursor[idx[i]], 1);
        csr2[p] = make_int2(i, src[i]);
    }
}

// payload = map[i] (or i if map==nullptr)
__global__ void fillm_k(const int* __restrict__ idx, const int* __restrict__ map,
                        int n, int* __restrict__ cursor, int* __restrict__ csr)
{
    int i = blockIdx.x * 256 + threadIdx.x;
    if (i < n) {
        int p = atomicAdd(&cursor[idx[i]], 1);
        csr[p] = map ? map[i] : i;
    }
}

// per-lane BN coefficients from raw sums (bn_finalize fused into consumers)
__device__ inline void bn_lane(const float* bsum, const float* bsq,
                               const float* bg, const float* bbe, float minv,
                               int lane, float& sc0, float& sc1, float& sh0, float& sh1)
{
    float mu0 = bsum[2 * lane] * minv,     mu1 = bsum[2 * lane + 1] * minv;
    float va0 = fmaxf(bsq[2 * lane] * minv - mu0 * mu0, 0.f);
    float va1 = fmaxf(bsq[2 * lane + 1] * minv - mu1 * mu1, 0.f);
    sc0 = bg[2 * lane] * rsqrtf(va0 + 1e-5f);
    sc1 = bg[2 * lane + 1] * rsqrtf(va1 + 1e-5f);
    sh0 = fmaf(-mu0, sc0, bbe[2 * lane]);
    sh1 = fmaf(-mu1, sc1, bbe[2 * lane + 1]);
}

// ---------------------------------------------------------------------------
// Atom GINE aggregation, STREAMING (R9-verified depth-1, NPW=8).
// ---------------------------------------------------------------------------
__global__ __launch_bounds__(256) void gine_agg_atom_b(
    const u32* __restrict__ x2, const float4* __restrict__ attrp,
    const int2* __restrict__ csr2, const int* __restrict__ rowptr,
    const float* __restrict__ Wm, const float* __restrict__ bm,
    const float* __restrict__ bsum, const float* __restrict__ bsq,
    const float* __restrict__ bg, const float* __restrict__ bbe,
    float bminv, int trelu,
    u32* __restrict__ out2, int n)
{
    const int lane = threadIdx.x & 63;
    const int v0 = (blockIdx.x * 4 + (threadIdx.x >> 6)) * NPW;
    if (v0 >= n) return;
    const int vend = (v0 + NPW < n) ? v0 + NPW : n;

    const float2 w0 = *(const float2*)&Wm[0 * 128 + 2 * lane];
    const float2 w1 = *(const float2*)&Wm[1 * 128 + 2 * lane];
    const float2 w2 = *(const float2*)&Wm[2 * 128 + 2 * lane];
    const float2 w3 = *(const float2*)&Wm[3 * 128 + 2 * lane];
    const float2 w4 = *(const float2*)&Wm[4 * 128 + 2 * lane];
    const float2 w5 = *(const float2*)&Wm[5 * 128 + 2 * lane];
    const float2 w6 = *(const float2*)&Wm[6 * 128 + 2 * lane];
    const float2 w7 = *(const float2*)&Wm[7 * 128 + 2 * lane];
    const float2 w8 = *(const float2*)&Wm[8 * 128 + 2 * lane];
    const float2 w9 = *(const float2*)&Wm[9 * 128 + 2 * lane];
    const float2 wa = *(const float2*)&Wm[10 * 128 + 2 * lane];
    const float2 bb = *(const float2*)&bm[2 * lane];

    float sc0 = 1.f, sc1 = 1.f, sh0 = 0.f, sh1 = 0.f;
    if (bsum) bn_lane(bsum, bsq, bg, bbe, bminv, lane, sc0, sc1, sh0, sh1);

    const int E0 = rowptr[v0], E1 = rowptr[vend];
    int v  = v0;
    int nb = rowptr[v0 + 1];
    u32 xs_n = (v0 + 1 < vend) ? x2[(size_t)(v0 + 1) * 64 + lane] : 0u;
    float2 acc = up2(x2[(size_t)v0 * 64 + lane]);
    acc.x = fmaf(acc.x, sc0, sh0); acc.y = fmaf(acc.y, sc1, sh1);
    if (trelu) { acc.x = fmaxf(acc.x, 0.f); acc.y = fmaxf(acc.y, 0.f); }

    if (E0 < E1) {
        int2 pc = csr2[E0];
        int2 pn = csr2[(E0 + 1 < E1) ? E0 + 1 : E0];
        float4 a0c = attrp[3 * (size_t)E0];
        float4 a1c = attrp[3 * (size_t)E0 + 1];
        float4 a2c = attrp[3 * (size_t)E0 + 2];
        u32 xc = x2[(size_t)pc.y * 64 + lane];
        for (int e = E0; e < E1; ++e) {
            const int en  = (e + 1 < E1) ? e + 1 : e;
            const int en2 = (e + 2 < E1) ? e + 2 : en;
            int2 p2 = csr2[en2];                     // payload 2 ahead
            u32 xn = x2[(size_t)pn.y * 64 + lane];   // gather via resident payload
            float4 a0n = attrp[3 * (size_t)en];
            float4 a1n = attrp[3 * (size_t)en + 1];
            float4 a2n = attrp[3 * (size_t)en + 2];
            // flush completed node(s) — wave-uniform branch
            while (e >= nb) {
                out2[(size_t)v * 64 + lane] = pk2(acc.x, acc.y);
                ++v;
                float2 nx = up2(xs_n);
                nx.x = fmaf(nx.x, sc0, sh0); nx.y = fmaf(nx.y, sc1, sh1);
                if (trelu) { nx.x = fmaxf(nx.x, 0.f); nx.y = fmaxf(nx.y, 0.f); }
                acc = nx;
                xs_n = (v + 1 < vend) ? x2[(size_t)(v + 1) * 64 + lane] : xs_n;
                nb = rowptr[v + 1];
            }
            // compute edge e (all operands resident, named regs only)
            float m0 = bb.x, m1 = bb.y;
            m0 = fmaf(a0c.x, w0.x, m0); m1 = fmaf(a0c.x, w0.y, m1);
            m0 = fmaf(a0c.y, w1.x, m0); m1 = fmaf(a0c.y, w1.y, m1);
            m0 = fmaf(a0c.z, w2.x, m0); m1 = fmaf(a0c.z, w2.y, m1);
            m0 = fmaf(a0c.w, w3.x, m0); m1 = fmaf(a0c.w, w3.y, m1);
            m0 = fmaf(a1c.x, w4.x, m0); m1 = fmaf(a1c.x, w4.y, m1);
            m0 = fmaf(a1c.y, w5.x, m0); m1 = fmaf(a1c.y, w5.y, m1);
            m0 = fmaf(a1c.z, w6.x, m0); m1 = fmaf(a1c.z, w6.y, m1);
            m0 = fmaf(a1c.w, w7.x, m0); m1 = fmaf(a1c.w, w7.y, m1);
            m0 = fmaf(a2c.x, w8.x, m0); m1 = fmaf(a2c.x, w8.y, m1);
            m0 = fmaf(a2c.y, w9.x, m0); m1 = fmaf(a2c.y, w9.y, m1);
            m0 = fmaf(a2c.z, wa.x, m0); m1 = fmaf(a2c.z, wa.y, m1);
            float2 s = up2(xc);
            s.x = fmaf(s.x, sc0, sh0); s.y = fmaf(s.y, sc1, sh1);
            if (trelu) { s.x = fmaxf(s.x, 0.f); s.y = fmaxf(s.y, 0.f); }
            acc.x += fmaxf(s.x + m0, 0.f);
            acc.y += fmaxf(s.y + m1, 0.f);
            // rotate
            pn = p2; xc = xn;
            a0c = a0n; a1c = a1n; a2c = a2n;
        }
    }
    // tail flush: nodes v .. vend-1
    for (;;) {
        out2[(size_t)v * 64 + lane] = pk2(acc.x, acc.y);
        ++v;
        if (v >= vend) break;
        float2 nx = up2(xs_n);
        nx.x = fmaf(nx.x, sc0, sh0); nx.y = fmaf(nx.y, sc1, sh1);
        if (trelu) { nx.x = fmaxf(nx.x, 0.f); nx.y = fmaxf(nx.y, 0.f); }
        acc = nx;
        xs_n = (v + 1 < vend) ? x2[(size_t)(v + 1) * 64 + lane] : xs_n;
    }
}

// fg aggregation, STREAMING depth-1 (R9-verified); eemb2 CSR-ORDERED.
__global__ __launch_bounds__(256) void gine_agg_pre_b(
    const u32* __restrict__ x2, const u32* __restrict__ eemb2,
    const int2* __restrict__ csr2, const int* __restrict__ rowptr,
    const float* __restrict__ bsum, const float* __restrict__ bsq,
    const float* __restrict__ bg, const float* __restrict__ bbe,
    float bminv, int trelu,
    u32* __restrict__ out2, int n)
{
    const int lane = threadIdx.x & 63;
    const int v0 = (blockIdx.x * 4 + (threadIdx.x >> 6)) * NPW;
    if (v0 >= n) return;
    const int vend = (v0 + NPW < n) ? v0 + NPW : n;

    float sc0 = 1.f, sc1 = 1.f, sh0 = 0.f, sh1 = 0.f;
    if (bsum) bn_lane(bsum, bsq, bg, bbe, bminv, lane, sc0, sc1, sh0, sh1);

    const int E0 = rowptr[v0], E1 = rowptr[vend];
    int v  = v0;
    int nb = rowptr[v0 + 1];
    u32 xs_n = (v0 + 1 < vend) ? x2[(size_t)(v0 + 1) * 64 + lane] : 0u;
    float2 acc = up2(x2[(size_t)v0 * 64 + lane]);
    acc.x = fmaf(acc.x, sc0, sh0); acc.y = fmaf(acc.y, sc1, sh1);
    if (trelu) { acc.x = fmaxf(acc.x, 0.f); acc.y = fmaxf(acc.y, 0.f); }

    if (E0 < E1) {
        int2 pc = csr2[E0];
        int2 pn = csr2[(E0 + 1 < E1) ? E0 + 1 : E0];
        u32 xc = x2[(size_t)pc.y * 64 + lane];
        u32 mc = eemb2[(size_t)E0 * 64 + lane];
        for (int e = E0; e < E1; ++e) {
            const int en  = (e + 1 < E1) ? e + 1 : e;
            const int en2 = (e + 2 < E1) ? e + 2 : en;
            int2 p2 = csr2[en2];
            u32 xn = x2[(size_t)pn.y * 64 + lane];
            u32 mn = eemb2[(size_t)en * 64 + lane];
            while (e >= nb) {
                out2[(size_t)v * 64 + lane] = pk2(acc.x, acc.y);
                ++v;
                float2 nx = up2(xs_n);
                nx.x = fmaf(nx.x, sc0, sh0); nx.y = fmaf(nx.y, sc1, sh1);
                if (trelu) { nx.x = fmaxf(nx.x, 0.f); nx.y = fmaxf(nx.y, 0.f); }
                acc = nx;
                xs_n = (v + 1 < vend) ? x2[(size_t)(v + 1) * 64 + lane] : xs_n;
                nb = rowptr[v + 1];
            }
            float2 m = up2(mc);
            float2 s = up2(xc);
            s.x = fmaf(s.x, sc0, sh0); s.y = fmaf(s.y, sc1, sh1);
            if (trelu) { s.x = fmaxf(s.x, 0.f); s.y = fmaxf(s.y, 0.f); }
            acc.x += fmaxf(m.x + s.x, 0.f);
            acc.y += fmaxf(m.y + s.y, 0.f);
            pn = p2; xc = xn; mc = mn;
        }
    }
    for (;;) {
        out2[(size_t)v * 64 + lane] = pk2(acc.x, acc.y);
        ++v;
        if (v >= vend) break;
        float2 nx = up2(xs_n);
        nx.x = fmaf(nx.x, sc0, sh0); nx.y = fmaf(nx.y, sc1, sh1);
        if (trelu) { nx.x = fmaxf(nx.x, 0.f); nx.y = fmaxf(nx.y, 0.f); }
        acc = nx;
        xs_n = (v + 1 < vend) ? x2[(size_t)(v + 1) * 64 + lane] : xs_n;
    }
}

// segment mean, bf16 -> bf16; post-mean affine from raw sums (empty seg -> 0)
__global__ __launch_bounds__(256) void seg_mean_b2b(
    const u32* __restrict__ x2, const int* __restrict__ csr,
    const int* __restrict__ rowptr,
    const float* __restrict__ bsum, const float* __restrict__ bsq,
    const float* __restrict__ bg, const float* __restrict__ bbe, float bminv,
    u32* __restrict__ out2, int n)
{
    const int lane = threadIdx.x & 63;
    const int v = blockIdx.x * 4 + (threadIdx.x >> 6);
    if (v >= n) return;
    const int e0 = rowptr[v], e1 = rowptr[v + 1];
    float2 acc = make_float2(0.f, 0.f);
    if (e0 < e1) {
        int cc = csr[e0];
        int cn = csr[(e0 + 1 < e1) ? e0 + 1 : e0];
        u32 xc = x2[(size_t)cc * 64 + lane];
        for (int e = e0; e < e1; ++e) {
            const int en  = (e + 1 < e1) ? e + 1 : e;
            const int en2 = (e + 2 < e1) ? e + 2 : en;
            int c2 = csr[en2];
            u32 xn = x2[(size_t)cn * 64 + lane];
            float2 s = up2(xc);
            acc.x += s.x; acc.y += s.y;
            cn = c2; xc = xn;
        }
    }
    float inv = 1.f / fmaxf((float)(e1 - e0), 1.f);
    float2 r = make_float2(acc.x * inv, acc.y * inv);
    if (bsum) {
        if (e1 > e0) {
            float sc0, sc1, sh0, sh1;
            bn_lane(bsum, bsq, bg, bbe, bminv, lane, sc0, sc1, sh0, sh1);
            r.x = fmaf(r.x, sc0, sh0);
            r.y = fmaf(r.y, sc1, sh1);
        } else {
            r.x = 0.f; r.y = 0.f;
        }
    }
    out2[(size_t)v * 64 + lane] = pk2(r.x, r.y);
}

// segment mean, bf16 -> fp32 (final), same post-mean affine
__global__ __launch_bounds__(256) void seg_mean_b2f(
    const u32* __restrict__ x2, const int* __restrict__ csr,
    const int* __restrict__ rowptr,
    const float* __restrict__ bsum, const float* __restrict__ bsq,
    const float* __restrict__ bg, const float* __restrict__ bbe, float bminv,
    float* __restrict__ out, int n)
{
    const int lane = threadIdx.x & 63;
    const int v = blockIdx.x * 4 + (threadIdx.x >> 6);
    if (v >= n) return;
    const int e0 = rowptr[v], e1 = rowptr[v + 1];
    float2 acc = make_float2(0.f, 0.f);
    if (e0 < e1) {
        int cc = csr[e0];
        int cn = csr[(e0 + 1 < e1) ? e0 + 1 : e0];
        u32 xc = x2[(size_t)cc * 64 + lane];
        for (int e = e0; e < e1; ++e) {
            const int en  = (e + 1 < e1) ? e + 1 : e;
            const int en2 = (e + 2 < e1) ? e + 2 : en;
            int c2 = csr[en2];
            u32 xn = x2[(size_t)cn * 64 + lane];
            float2 s = up2(xc);
            acc.x += s.x; acc.y += s.y;
            cn = c2; xc = xn;
        }
    }
    float inv = 1.f / fmaxf((float)(e1 - e0), 1.f);
    float2 r = make_float2(acc.x * inv, acc.y * inv);
    if (bsum) {
        if (e1 > e0) {
            float sc0, sc1, sh0, sh1;
            bn_lane(bsum, bsq, bg, bbe, bminv, lane, sc0, sc1, sh0, sh1);
            r.x = fmaf(r.x, sc0, sh0);
            r.y = fmaf(r.y, sc1, sh1);
        } else {
            r.x = 0.f; r.y = 0.f;
        }
    }
    *(float2*)&out[(size_t)v * 128 + lane * 2] = r;
}

// ---------------------------------------------------------------------------
extern "C" void kernel_launch(void* const* d_in, const int* in_sizes, int n_in,
                              void* d_out, int out_size, void* d_ws, size_t ws_size,
                              hipStream_t stream)
{
    const float* atom_x        = (const float*)d_in[0];
    const float* fg_x          = (const float*)d_in[1];
    const float* atom_edge_attr= (const float*)d_in[2];
    const float* fg_edge_attr  = (const float*)d_in[3];
    const float* atom_emb_W    = (const float*)d_in[4];
    const float* atom_emb_b    = (const float*)d_in[5];
    const float* fg_emb_W      = (const float*)d_in[6];
    const float* fg_emb_b      = (const float*)d_in[7];
    const float* bond_W        = (const float*)d_in[8];
    const float* bond_b        = (const float*)d_in[9];
    const float* ag_W1         = (const float*)d_in[10];
    const float* ag_b1         = (const float*)d_in[11];
    const float* ag_g1         = (const float*)d_in[12];
    const float* ag_be1        = (const float*)d_in[13];
    const float* ag_W2         = (const float*)d_in[14];
    const float* ag_b2         = (const float*)d_in[15];
    const float* abn_g         = (const float*)d_in[16];
    const float* abn_b         = (const float*)d_in[17];
    const float* fge_W         = (const float*)d_in[18];
    const float* fge_b         = (const float*)d_in[19];
    const float* fg_W1         = (const float*)d_in[20];
    const float* fg_b1         = (const float*)d_in[21];
    const float* fg_g1         = (const float*)d_in[22];
    const float* fg_be1        = (const float*)d_in[23];
    const float* fg_W2         = (const float*)d_in[24];
    const float* fg_b2         = (const float*)d_in[25];
    const float* fbn_g         = (const float*)d_in[26];
    const float* fbn_b         = (const float*)d_in[27];
    const float* a2f_W         = (const float*)d_in[28];
    const float* a2f_b         = (const float*)d_in[29];
    const int*   aei           = (const int*)d_in[30];
    const int*   fei           = (const int*)d_in[31];
    const int*   atom_idx      = (const int*)d_in[32];
    const int*   fg_idx        = (const int*)d_in[33];
    const int*   fg_batch      = (const int*)d_in[34];
    const int *asrc = aei, *adst = aei + EA_C;
    const int *fsrc = fei, *fdst = fei + EF_C;

    // ---- workspace carving (bytes) ----
    char* base = (char*)d_ws;
    const size_t SZ_H = (size_t)NA_C * DD * 2;        // 51.2 MB bf16 node slot
    u16* hA = (u16*)base;                             // h ping
    u16* hB = (u16*)(base + SZ_H);                    // h pong
    u16* TB = (u16*)(base + 2 * SZ_H);                // t (NA x 256 bf16, 102.4 MB)
    u16* XB = (u16*)(base + 2 * SZ_H + (size_t)NA_C * HH * 2);  // atom_x_bf / attr_perm / fg_attr_bf
    char* csrb = (char*)XB + SZ_H;                    // CSR area (16B aligned)
    int*  aR  = (int*)csrb;                           // rowptr (max NA+1)
    int*  aCu = aR + (NA_C + 2);                      // cursor/deg (max NA)
    int*  bS  = aCu + NA_C;                           // scan partials (256)
    int2* aE2 = (int2*)(bS + 258);                    // payload (max EA int2)
    char* wtb = (char*)(aE2 + EA_C);
    wtb = (char*)(((uintptr_t)wtb + 15) & ~(uintptr_t)15);   // 16B align
    u16* WT_aemb = (u16*)wtb;                 wtb += 128 * 128 * 2;
    u16* WT_aW1  = (u16*)wtb;                 wtb += 3 * 256 * 128 * 2;
    u16* WT_aW2  = (u16*)wtb;                 wtb += 3 * 128 * 256 * 2;
    u16* WT_a2f  = (u16*)wtb;                 wtb += 128 * 128 * 2;
    u16* WT_femb = (u16*)wtb;                 wtb += 128 * 128 * 2;   // Kp=128
    u16* WT_fge  = (u16*)wtb;                 wtb += 2 * 128 * 128 * 2;
    u16* WT_fW1  = (u16*)wtb;                 wtb += 2 * 256 * 128 * 2;
    u16* WT_fW2  = (u16*)wtb;                 wtb += 2 * 128 * 256 * 2;
    // per-stage BN stats arena: 10 stages x {sum,sq} x 256 floats, zeroed once
    float* stats = (float*)wtb;               wtb += 5120 * sizeof(float);
    float* S_SUM = stats;            // + st*256
    float* S_SQ  = stats + 2560;

    // ---- ALL weight preps in one launch ----
    {
        WtJobs jb;
        int t = 0, acc = 0;
        auto add = [&](const float* W, u16* Wt, int K, int N, int Kp) {
            jb.W[t] = W; jb.Wt[t] = Wt; jb.K[t] = K; jb.N[t] = N; jb.Kp[t] = Kp;
            acc += N * Kp; jb.end[t] = acc; ++t;
        };
        add(atom_emb_W, WT_aemb, 101, 128, 128);
        add(a2f_W,      WT_a2f,  128, 128, 128);
        for (int i = 0; i < 3; ++i)
            add(ag_W1 + (size_t)i * 128 * 256, WT_aW1 + (size_t)i * 256 * 128, 128, 256, 128);
        for (int i = 0; i < 3; ++i)
            add(ag_W2 + (size_t)i * 256 * 128, WT_aW2 + (size_t)i * 128 * 256, 256, 128, 256);
        add(fg_emb_W,   WT_femb, 73, 128, 128);   // Kp padded 96 -> 128 (BK=64)
        for (int i = 0; i < 2; ++i)
            add(fge_W + (size_t)i * 101 * 128, WT_fge + (size_t)i * 128 * 128, 101, 128, 128);
        for (int i = 0; i < 2; ++i)
            add(fg_W1 + (size_t)i * 128 * 256, WT_fW1 + (size_t)i * 256 * 128, 128, 256, 128);
        for (int i = 0; i < 2; ++i)
            add(fg_W2 + (size_t)i * 256 * 128, WT_fW2 + (size_t)i * 128 * 256, 256, 128, 256);
        prep_wt_all<<<(acc + 255) / 256, 256, 0, stream>>>(jb, acc);
    }
    hipMemsetAsync(stats, 0, 5120 * sizeof(float), stream);   // all sums+sqs

    // ---- atom CSR (dst-sorted, payload (eid, src)) ----
    csr_prefix(stream, adst, EA_C, NA_C, aR, aCu, bS);
    fill2_k<<<(EA_C + 255) / 256, 256, 0, stream>>>(adst, asrc, EA_C, aCu, aE2);

    // ---- atom_x -> bf16 padded [NA,128] (XB) ----
    cvt_pad<<<((size_t)NA_C * 64 + 255) / 256, 256, 0, stream>>>(atom_x, (u32*)XB, NA_C, 101, 64);

    // ---- atom embedding (consumes XB) ----
    gemm_launch(stream, XB, WT_aemb, atom_emb_b,
                nullptr, nullptr, nullptr, nullptr, 0.f, nullptr, hA, NA_C, 128, 128);

    // ---- attr -> CSR-permuted [EA,12] fp32 (reuses XB) ----
    float* attrP = (float*)XB;
    perm_attr12_k<<<((size_t)EA_C * 12 + 255) / 256, 256, 0, stream>>>(
        atom_edge_attr, aE2, attrP, EA_C);

    // ---- 3 atom GINE layers (hA <-> hB ping-pong) ----
    const int agrid = (NA_C + 4 * NPW - 1) / (4 * NPW);
    u16* hc = hA;
    const float* cb_sum = nullptr; const float* cb_sq = nullptr;
    const float* cb_g = nullptr;   const float* cb_be = nullptr;
    int cur_relu = 0;
    for (int i = 0; i < 3; ++i) {
        u16* hn = (hc == hA) ? hB : hA;
        const int st1 = 2 * i, st2 = 2 * i + 1;
        gine_agg_atom_b<<<agrid, 256, 0, stream>>>(
            (const u32*)hc, (const float4*)attrP, aE2, aR,
            bond_W + (size_t)i * 11 * DD, bond_b + i * DD,
            cb_sum, cb_sq, cb_g, cb_be, 1.f / NA_C, cur_relu, (u32*)hn, NA_C);
        gemm_launch(stream, hn, WT_aW1 + (size_t)i * 256 * 128,
                    ag_b1 + i * HH, nullptr, nullptr, nullptr, nullptr, 0.f,
                    nullptr, TB, NA_C, 128, HH,
                    S_SUM + st1 * 256, S_SQ + st1 * 256);
        gemm_launch(stream, TB, WT_aW2 + (size_t)i * 128 * 256,
                    ag_b2 + i * DD,
                    S_SUM + st1 * 256, S_SQ + st1 * 256,
                    ag_g1 + i * HH, ag_be1 + i * HH, 1.f / NA_C,
                    nullptr, hn, NA_C, 256, 128,
                    S_SUM + st2 * 256, S_SQ + st2 * 256);
        cb_sum = S_SUM + st2 * 256; cb_sq = S_SQ + st2 * 256;
        cb_g = abn_g + i * DD; cb_be = abn_b + i * DD;
        cur_relu = (i != 2);
        hc = hn;
    }
    // hc == hB (h3, raw); cb_* hold atom BN2[2] raw stats (affine, no relu)

    // ---- a2f: means = seg_mean(bn(h3)[atom_idx], fg_idx, NF) @ a2f_W + b ----
    {
        int* xE = (int*)aE2;
        csr_prefix(stream, fg_idx, NA_C, NF_C, aR, aCu, bS);
        fillm_k<<<(NA_C + 255) / 256, 256, 0, stream>>>(fg_idx, atom_idx, NA_C, aCu, xE);
        seg_mean_b2b<<<(NF_C + 3) / 4, 256, 0, stream>>>(
            (const u32*)hc, xE, aR, cb_sum, cb_sq, cb_g, cb_be, 1.f / NA_C,
            (u32*)hA, NF_C);
    }
    u16* means   = hA;                                  // [NF,128]
    u16* a2f_lin = hA + (size_t)NF_C * DD;              // [NF,128]
    gemm_launch(stream, means, WT_a2f, a2f_b,
                nullptr, nullptr, nullptr, nullptr, 0.f, nullptr, a2f_lin, NF_C, 128, 128);

    // ---- fg embedding: g = fg_x @ femb + b + a2f_lin  (K padded to 128) ----
    u16* fgx_bf = hA + 2 * (size_t)NF_C * DD;           // [NF,128]
    cvt_pad<<<((size_t)NF_C * 64 + 255) / 256, 256, 0, stream>>>(fg_x, (u32*)fgx_bf, NF_C, 73, 64);
    u16* g = hB;
    gemm_launch(stream, fgx_bf, WT_femb, fg_emb_b,
                nullptr, nullptr, nullptr, nullptr, 0.f, a2f_lin, g, NF_C, 128, 128);

    // ---- fg CSR FIRST, then fg edge attr -> bf16 [EF,128] in CSR order ----
    csr_prefix(stream, fdst, EF_C, NF_C, aR, aCu, bS);
    fill2_k<<<(EF_C + 255) / 256, 256, 0, stream>>>(fdst, fsrc, EF_C, aCu, aE2);
    cvt_pad_perm<<<((size_t)EF_C * 64 + 255) / 256, 256, 0, stream>>>(
        fg_edge_attr, aE2, (u32*)XB, EF_C, 101, 64);

    // ---- 2 fg GINE layers (g stored raw; consumer applies BN inline) ----
    const int fgrid = (NF_C + 4 * NPW - 1) / (4 * NPW);
    u16* eemb = TB;                                     // [EF,128] bf16
    u16* gn   = hA + 3 * (size_t)NF_C * DD;             // [NF,128]
    u16* gt   = TB + (size_t)EF_C * DD;                 // [NF,256]
    const float* gb_sum = nullptr; const float* gb_sq = nullptr;
    const float* gb_g = nullptr;   const float* gb_be = nullptr;
    int grelu = 0;
    for (int i = 0; i < 2; ++i) {
        const int st1 = 6 + 2 * i, st2 = 7 + 2 * i;
        gemm_launch(stream, XB, WT_fge + (size_t)i * 128 * 128,
                    fge_b + i * DD, nullptr, nullptr, nullptr, nullptr, 0.f,
                    nullptr, eemb, EF_C, 128, 128);
        gine_agg_pre_b<<<fgrid, 256, 0, stream>>>(
            (const u32*)g, (const u32*)eemb, aE2, aR,
            gb_sum, gb_sq, gb_g, gb_be, 1.f / NF_C, grelu, (u32*)gn, NF_C);
        gemm_launch(stream, gn, WT_fW1 + (size_t)i * 256 * 128,
                    fg_b1 + i * HH, nullptr, nullptr, nullptr, nullptr, 0.f,
                    nullptr, gt, NF_C, 128, HH,
                    S_SUM + st1 * 256, S_SQ + st1 * 256);
        gemm_launch(stream, gt, WT_fW2 + (size_t)i * 128 * 256,
                    fg_b2 + i * DD,
                    S_SUM + st1 * 256, S_SQ + st1 * 256,
                    fg_g1 + i * HH, fg_be1 + i * HH, 1.f / NF_C,
                    nullptr, g, NF_C, 256, 128,
                    S_SUM + st2 * 256, S_SQ + st2 * 256);
        gb_sum = S_SUM + st2 * 256; gb_sq = S_SQ + st2 * 256;
        gb_g = fbn_g + i * DD; gb_be = fbn_b + i * DD;
        grelu = (i != 1);
    }
    // gb_* hold fg BN2[1] raw stats (affine, no relu) -> applied post-mean

    // ---- final seg_mean(bn(g), fg_batch, NG) -> d_out fp32 ----
    {
        int* bR  = (int*)(gt + (size_t)NF_C * HH);
        int* bCu = bR + (NG_C + 1);
        int* bE  = bCu + NG_C;
        csr_prefix(stream, fg_batch, NF_C, NG_C, bR, bCu, bS);
        fillm_k<<<(NF_C + 255) / 256, 256, 0, stream>>>(fg_batch, nullptr, NF_C, bCu, bE);
        seg_mean_b2f<<<(NG_C + 3) / 4, 256, 0, stream>>>(
            (const u32*)g, bE, bR, gb_sum, gb_sq, gb_g, gb_be, 1.f / NF_C,
            (float*)d_out, NG_C);
    }
}